// Round 1
// baseline (282.333 us; speedup 1.0000x reference)
//
#include <hip/hip_runtime.h>
#include <stdint.h>

// MVDR oracle beamformer — MI355X (gfx950)
// Phase A: per-(n,f) Hermitian covariance partial sums over t-chunks.
//   R5 evidence: VGPR_Count=96 < 136 needed for the register PIPE=4 ->
//   compiler collapsed the pipeline; ~2 loads in flight/wave -> latency-bound
//   (VALUBusy 13.7%, HBM 25%, occ 17.5%). This version stages through LDS via
//   global_load_lds (in-flight data costs ZERO VGPRs), 3-deep ring with
//   hand-counted s_waitcnt vmcnt(N) (T3/T4 pattern): 48 loads = 12 KB in
//   flight per wave by construction. Single-wave blocks -> no barriers needed.
// Phase B1: float4 parallel reduction of the t-chunks (into chunk-0 slot).
// Phase B2: streaming solve — invert phi_v (unpivoted GJ, diag-dominant),
//           build W = conj(H).
// Phase C: beamform X = sum_c W[c] * y[c].

constexpr int N_  = 8;
constexpr int C_  = 8;
constexpr int T_  = 600;
constexpr int F_  = 257;
constexpr int TF_  = T_ * F_;       // 154200
constexpr int CTF_ = C_ * TF_;      // 1233600
constexpr int NSTR_ = 2 * CTF_;     // per-batch stride in inputs
constexpr int NF_  = N_ * F_;       // 2056
constexpr int NPAIR_ = 36;          // lower-triangle pairs of 8x8 Hermitian
constexpr float LOADC_ = 7.0710678118654755e-4f;  // 0.001/sqrt(2)
constexpr float INV_T_ = 1.0f / 600.0f;

struct cx { float r, i; };
__device__ __forceinline__ cx cmul(cx a, cx b) { return {a.r*b.r - a.i*b.i, a.r*b.i + a.i*b.r}; }
__device__ __forceinline__ cx csub(cx a, cx b) { return {a.r - b.r, a.i - b.i}; }
__device__ __forceinline__ cx cconj(cx a) { return {a.r, -a.i}; }
__device__ __forceinline__ cx cinv(cx a) {
    float id = 1.0f / (a.r*a.r + a.i*a.i);
    return {a.r*id, -a.i*id};
}
__device__ __forceinline__ cx cmadd(cx acc, cx a, cx b) {
    acc.r += a.r*b.r - a.i*b.i;
    acc.i += a.r*b.i + a.i*b.r;
    return acc;
}

// Async global->LDS, 4 B per lane. LDS dest is wave-uniform base + lane*4;
// global src is per-lane.
__device__ __forceinline__ void gload_lds4(const float* g, float* l) {
    __builtin_amdgcn_global_load_lds(
        (const __attribute__((address_space(1))) void*)g,
        (__attribute__((address_space(3))) void*)l,
        4, 0, 0);
}

#define VMWAIT(N) asm volatile("s_waitcnt vmcnt(" #N ")" ::: "memory")
#define LGKM0()   asm volatile("s_waitcnt lgkmcnt(0)" ::: "memory")

// ---------------------------------------------------------------------------
// Phase A: partial covariance sums, LDS-staged 3-deep async ring over t.
// grid (5, N, 2*TSPLIT), block 64 (1 wave). Thread owns one f; z&1 selects
// source (0 = noise -> phi_v, 1 = mixture -> phi_y); z>>1 selects t-chunk.
// Partial layout: part[((m*TSPLIT + chunk)*72 + (2p+ri)) * NF + n*F + f]
//
// Ring discipline (16 loads per t-slot, issued oldest-first):
//   steady state: 3 slots outstanding (48 loads); wait vmcnt(32) -> oldest
//   slot landed. Tail: waits 32 -> 16 -> 0 as staging stops.
// Single wave per block: no s_barrier anywhere; lgkmcnt(0) guards the slot
// about to be overwritten (its ds_reads are consumed by then anyway).
// ---------------------------------------------------------------------------
template<int TSPLIT>
__global__ __launch_bounds__(64, 1) void cov_partial(
        const float* __restrict__ mix, const float* __restrict__ noi,
        float* __restrict__ part) {
    constexpr int TCHUNK = T_ / TSPLIT;
    constexpr int P = 3;
    static_assert(TCHUNK % P == 0 && TCHUNK > P, "ring/chunk mismatch");

    __shared__ float S[P][16][64];   // [slot][row = 2c+ri][f-lane]  12 KB

    const int lane = threadIdx.x;
    const int f = blockIdx.x * 64 + lane;
    if (f >= F_) return;
    const int n = blockIdx.y;
    const int z = blockIdx.z;
    const int m = z & 1;
    const int chunk = z >> 1;
    const float* src = (m ? mix : noi) + (size_t)n * NSTR_
                     + (size_t)(chunk * TCHUNK) * F_ + f;

    // Stage time-step t into slot s: 16 rows (c, ri), 256 B each.
    auto stage = [&](int s, int t) {
        const float* pg = src + (size_t)t * F_;
        float* lp = &S[s][0][0];
#pragma unroll
        for (int c = 0; c < C_; ++c) {
            gload_lds4(pg + (size_t)c * TF_,        lp + (2*c)   * 64);
            gload_lds4(pg + (size_t)c * TF_ + CTF_, lp + (2*c+1) * 64);
        }
    };

    float accr[NPAIR_], acci[NPAIR_];
#pragma unroll
    for (int p = 0; p < NPAIR_; ++p) { accr[p] = 0.f; acci[p] = 0.f; }

    auto consume = [&](int s) {
        float re[C_], im[C_];
#pragma unroll
        for (int c = 0; c < C_; ++c) {
            re[c] = S[s][2*c][lane];      // ds_read2_b32 candidates (off +64)
            im[c] = S[s][2*c+1][lane];
        }
        int p = 0;
#pragma unroll
        for (int c = 0; c < C_; ++c) {
#pragma unroll
            for (int d = 0; d <= c; ++d, ++p) {
                accr[p] += re[c]*re[d] + im[c]*im[d];
                acci[p] += im[c]*re[d] - re[c]*im[d];
            }
        }
    };

    // Prologue: fill the ring (48 loads in flight, <= vmcnt max 63).
    stage(0, 0); stage(1, 1); stage(2, 2);

    // Main loop: t = 0 .. TCHUNK-P-1, always re-staging t+P.
    for (int tb = 0; tb < TCHUNK - P; tb += P) {
        VMWAIT(32); consume(0); LGKM0(); stage(0, tb + 3);
        VMWAIT(32); consume(1); LGKM0(); stage(1, tb + 4);
        VMWAIT(32); consume(2); LGKM0(); stage(2, tb + 5);
    }
    // Epilogue: last P slots, counted drains (32 -> 16 -> 0).
    VMWAIT(32); consume(0);
    VMWAIT(16); consume(1);
    VMWAIT(0);  consume(2);

    float* out = part + (size_t)((m * TSPLIT + chunk) * 72) * NF_ + n * F_ + f;
#pragma unroll
    for (int p = 0; p < NPAIR_; ++p) {
        out[(size_t)(2*p)   * NF_] = accr[p];
        out[(size_t)(2*p+1) * NF_] = acci[p];
    }
}

// ---------------------------------------------------------------------------
// Phase B1: reduce the chunks into the chunk-0 slot, float4-vectorized.
// One thread per (m, q, idx4): 2*72*514 = 74016 threads. All strides are
// multiples of NF_ floats = 8224 B (16B-aligned), idx4*16 B aligned.
// ---------------------------------------------------------------------------
__global__ __launch_bounds__(256) void reduce_cov(float* __restrict__ part, int tsplit) {
    int flat = blockIdx.x * 256 + threadIdx.x;
    constexpr int NQ4 = NF_ / 4;   // 514
    if (flat >= 2 * 72 * NQ4) return;
    int idx4 = flat % NQ4;
    int z = flat / NQ4;          // z = m*72 + q
    int m = z / 72;
    int q = z % 72;
    const float4* p4 = (const float4*)(part) + ((size_t)((m * tsplit) * 72 + q) * NF_) / 4 + idx4;
    float4 s = {0.f, 0.f, 0.f, 0.f};
    for (int ch = 0; ch < tsplit; ++ch) {
        float4 v = p4[(size_t)(ch * 72) * NF_ / 4];
        s.x += v.x; s.y += v.y; s.z += v.z; s.w += v.w;
    }
    *(float4*)((float*)part + (size_t)((m * tsplit) * 72 + q) * NF_ + idx4 * 4) = s;
}

// ---------------------------------------------------------------------------
// Phase B2: streaming solve. One thread per (n,f). yBase = tsplit*72*NF_.
// ---------------------------------------------------------------------------
__global__ __launch_bounds__(64, 1) void solve_w(
        const float* __restrict__ part, float* __restrict__ W, size_t yBase) {
    int idx = blockIdx.x * 64 + threadIdx.x;  // idx = n*F + f
    if (idx >= NF_) return;

    const float* pv = part + idx;            // m=0, chunk 0
    const float* py = part + yBase + idx;    // m=1, chunk 0

    // Build M = phi_v/T + LOAD*(1+i)*I directly from loads.
    cx M[64];
#pragma unroll
    for (int c = 0; c < 8; ++c) {
#pragma unroll
        for (int d = 0; d <= c; ++d) {
            int p = c*(c+1)/2 + d;
            cx val = { pv[(size_t)(2*p) * NF_] * INV_T_,
                       pv[(size_t)(2*p+1) * NF_] * INV_T_ };
            if (d == c) { val.r += LOADC_; val.i += LOADC_; }
            M[c*8 + d] = val;
            if (d < c) M[d*8 + c] = cconj(val);
        }
    }

    // In-place Gauss-Jordan inverse, no pivoting (diagonally dominant).
#pragma unroll
    for (int k = 0; k < 8; ++k) {
        cx p = cinv(M[k*8 + k]);
        M[k*8 + k] = p;
#pragma unroll
        for (int j = 0; j < 8; ++j) {
            if (j != k) M[k*8 + j] = cmul(M[k*8 + j], p);
        }
#pragma unroll
        for (int i = 0; i < 8; ++i) {
            if (i == k) continue;
            cx fkt = M[i*8 + k];
#pragma unroll
            for (int j = 0; j < 8; ++j) {
                if (j != k) M[i*8 + j] = csub(M[i*8 + j], cmul(fkt, M[k*8 + j]));
            }
            cx t = cmul(fkt, p);
            M[i*8 + k] = { -t.r, -t.i };
        }
    }

    // Stream the 36 stored y-pairs: yv = phi_y[a][b] (a >= b), scaled by 1/T.
    cx tr = {0.f, 0.f};
    cx g0[8];
#pragma unroll
    for (int c = 0; c < 8; ++c) g0[c] = (cx){0.f, 0.f};

#pragma unroll
    for (int a = 0; a < 8; ++a) {
#pragma unroll
        for (int b = 0; b <= a; ++b) {
            int p = a*(a+1)/2 + b;
            cx yv = { py[(size_t)(2*p) * NF_] * INV_T_,
                      py[(size_t)(2*p+1) * NF_] * INV_T_ };
            tr = cmadd(tr, M[b*8 + a], yv);
            if (a != b) tr = cmadd(tr, M[a*8 + b], cconj(yv));
            if (b == 0) {
#pragma unroll
                for (int i = 0; i < 8; ++i) g0[i] = cmadd(g0[i], M[i*8 + a], yv);
            }
        }
    }

    cx l = { tr.r - 8.0f, tr.i - 8.0f };
    float iden = 1.0f / (l.r*l.r + l.i*l.i);

    float* w = W + (size_t)idx * 16;
#pragma unroll
    for (int c = 0; c < 8; ++c) {
        cx ge = g0[c];
        if (c == 0) ge.r -= 1.0f;
        // W = conj(H) = conj(ge) * l / |l|^2
        w[2*c]     = (ge.r*l.r + ge.i*l.i) * iden;
        w[2*c + 1] = (ge.r*l.i - ge.i*l.r) * iden;
    }
}

// ---------------------------------------------------------------------------
// Phase C: beamform. grid (ceil(TF/256), N), block 256. Thread owns flat j=t*F+f.
// ---------------------------------------------------------------------------
__global__ __launch_bounds__(256) void beamform(
        const float* __restrict__ mix, const float* __restrict__ W,
        float* __restrict__ out) {
    int n = blockIdx.y;
    int j = blockIdx.x * 256 + threadIdx.x;
    if (j >= TF_) return;
    int f = j % F_;

    const float4* w4 = (const float4*)(W + (size_t)(n * F_ + f) * 16);
    float4 q0 = w4[0], q1 = w4[1], q2 = w4[2], q3 = w4[3];
    float wv[16] = { q0.x, q0.y, q0.z, q0.w,
                     q1.x, q1.y, q1.z, q1.w,
                     q2.x, q2.y, q2.z, q2.w,
                     q3.x, q3.y, q3.z, q3.w };

    const float* base = mix + (size_t)n * NSTR_ + j;
    float xr = 0.f, xi = 0.f;
#pragma unroll
    for (int c = 0; c < C_; ++c) {
        float yr = base[(size_t)c * TF_];
        float yi = base[(size_t)c * TF_ + CTF_];
        float wr = wv[2*c], wi = wv[2*c + 1];
        xr += wr*yr - wi*yi;
        xi += wr*yi + wi*yr;
    }
    float* op = out + (size_t)n * (2 * TF_);
    op[j]       = xr;
    op[TF_ + j] = xi;
}

extern "C" void kernel_launch(void* const* d_in, const int* in_sizes, int n_in,
                              void* d_out, int out_size, void* d_ws, size_t ws_size,
                              hipStream_t stream) {
    const float* mix = (const float*)d_in[0];
    // d_in[1] = target, unused by the reference
    const float* noi = (const float*)d_in[2];

    // TSPLIT=25 needs 2*25*72*NF + 16*NF floats of scratch (~29.7 MB).
    const size_t need25 = ((size_t)2 * 25 * 72 * NF_ + (size_t)16 * NF_) * 4;
    float* part = (float*)d_ws;
    int tsplit;
    if (ws_size >= need25) {
        tsplit = 25;   // TCHUNK=24 (div by ring depth 3): 2000 waves, ~7.8/CU
        cov_partial<25><<<dim3(5, N_, 2 * 25), 64, 0, stream>>>(mix, noi, part);
    } else {
        tsplit = 20;   // fallback, TCHUNK=30 (div by 3)
        cov_partial<20><<<dim3(5, N_, 2 * 20), 64, 0, stream>>>(mix, noi, part);
    }
    float* W = part + (size_t)2 * tsplit * 72 * NF_;

    reduce_cov<<<dim3((2 * 72 * (NF_ / 4) + 255) / 256), 256, 0, stream>>>(part, tsplit);
    solve_w<<<dim3((NF_ + 63) / 64), 64, 0, stream>>>(part, W, (size_t)tsplit * 72 * NF_);
    beamform<<<dim3((TF_ + 255) / 256, N_), 256, 0, stream>>>(mix, W, (float*)d_out);
}